// Round 7
// baseline (7040.628 us; speedup 1.0000x reference)
//
#include <hip/hip_runtime.h>

#define BATCH 64
#define SEQ 8192
#define RDIM 80
#define RING 169          // max delay 168 + 1
#define NCHUNK (SEQ / 2)  // 2 steps per chunk, 1 barrier per chunk

typedef float v2f __attribute__((ext_vector_type(2)));

__device__ __forceinline__ float fast_tanh(float z) {
    // tanh(z) = 1 - 2/(exp(2z)+1); exact saturation, abs err ~1e-7
    float e = __expf(2.0f * z);
    return 1.0f - 2.0f / (e + 1.0f);
}

// v + (v from lane ^ pattern) via DPP quad_perm (pure VALU, no LDS/SGPR hazard)
// 0xB1 = quad_perm(1,0,3,2) -> xor 1 ; 0x4E = quad_perm(2,3,0,1) -> xor 2
template <int CTRL>
__device__ __forceinline__ float dpp_xor_add(float v) {
    int o = __builtin_amdgcn_mov_dpp(__float_as_int(v), CTRL, 0xF, 0xF, true);
    return v + __int_as_float(o);
}

// TWO batches per block, interleaved IN-WAVE (ILP): 256 threads = 4 waves =
// 1 wave/SIMD (full reg budget, no co-wave issue competition, 4-wave barrier).
// Weights are shared across the batch pair; both batches' LDS roundtrips issue
// together and wait once. 32 blocks, 1 block/CU, LDS ~110 KB.
__global__ __attribute__((amdgpu_flat_work_group_size(256, 256),
                          amdgpu_waves_per_eu(1, 1)))
void reservoir_kernel(const float* __restrict__ x,
                      const float* __restrict__ W_in,
                      const float* __restrict__ W_fb,
                      const float* __restrict__ bias,
                      float* __restrict__ out) {
    // per-batch: ring[slot][i] = accumulated far-tap contributions for step s = slot (mod 169)
    __shared__ __align__(16) float ring[2 * RING * RDIM];    // 108160 B
    // per-batch: h_hist[s&3][i]: h for step s; rec wave writes, taps + rec-broadcast read
    __shared__ __align__(16) float h_hist[2 * 4 * RDIM];     // 2560 B

    const int t    = threadIdx.x;
    const int wid  = t >> 6;   // 0 = recurrence, 1..3 = taps (one SIMD each)
    const int lane = t & 63;
    const int b0   = blockIdx.x * 2;

    for (int i = t; i < 2 * RING * RDIM; i += 256) ring[i] = 0.0f;
    for (int i = t; i < 2 * 4 * RDIM; i += 256) h_hist[i] = 0.0f;

    float* ringp[2] = { ring, ring + RING * RDIM };
    float* hhp[2]   = { h_hist, h_hist + 4 * RDIM };
    const float* xb[2] = { x + (size_t)b0 * SEQ, x + (size_t)(b0 + 1) * SEQ };
    float* ob[2] = { out + (size_t)b0 * (size_t)SEQ * RDIM,
                     out + (size_t)(b0 + 1) * (size_t)SEQ * RDIM };

    v2f wr2[80];   // per-lane weight slice, SHARED by both batches (rec uses first 50)

    // ---- rec-wave layout: quad q owns rows 5q..5q+4; lane (q,sub) covers j in [20*sub, 20*sub+20)
    int q = 0, sub = 0, rowA = 0, rowB = 0;
    float winA = 0.f, winB = 0.f, bA = 0.f, bB = 0.f;
    float hA[2] = {0.f, 0.f}, hB[2] = {0.f, 0.f};
    v2f hh2[2][10];   // rec: per-batch broadcast h_{s-1} slice, carried across steps
    // ---- tap layout (waves 1..3, both steps, both batches):
    //      unit g = (wid-1)*64+lane < 160 ; k=g/40 -> tau{4,24,96,168};
    //      qq=(g%40)/2 -> rows 4qq..4qq+3 ; half=g&1 -> j in [40*half, 40*half+40)
    int tap_tau = 0, qq = 0, half = 0;
    bool tap_valid = false, tap_lo = false;
    float x0[2] = {0.f, 0.f}, x1[2] = {0.f, 0.f};

    if (wid == 0) {
        q = lane >> 2; sub = lane & 3;
        rowA = 5 * q + sub;        // owned by this lane
        rowB = 5 * q + 4;          // owned by sub==0 lane
        #pragma unroll
        for (int r = 0; r < 5; ++r) {
            const float* src = W_fb + (size_t)(5 * q + r) * RDIM + 20 * sub;  // W_1 rows
            #pragma unroll
            for (int j4 = 0; j4 < 5; ++j4) {
                float4 v = ((const float4*)src)[j4];
                wr2[r * 10 + 2 * j4 + 0] = (v2f){v.x, v.y};
                wr2[r * 10 + 2 * j4 + 1] = (v2f){v.z, v.w};
            }
        }
        winA = W_in[rowA]; bA = bias[rowA];
        winB = W_in[rowB]; bB = bias[rowB];
        #pragma unroll
        for (int pb = 0; pb < 2; ++pb)
            #pragma unroll
            for (int j2 = 0; j2 < 10; ++j2) hh2[pb][j2] = (v2f){0.f, 0.f};   // h_{-1} = 0
        x0[0] = xb[0][0]; x1[0] = xb[0][1];
        x0[1] = xb[1][0]; x1[1] = xb[1][1];
    } else {
        int g = (wid - 1) * 64 + lane;
        tap_valid = (g < 160);
        int gg = tap_valid ? g : 159;
        int k = gg / 40, rem = gg % 40;
        qq = rem >> 1; half = rem & 1;
        tap_lo = (half == 0);
        const int taus[4] = {4, 24, 96, 168};
        tap_tau = taus[k];
        #pragma unroll
        for (int r = 0; r < 4; ++r) {
            const float* src = W_fb + (size_t)(k + 1) * RDIM * RDIM
                                    + (size_t)(4 * qq + r) * RDIM + 40 * half;
            #pragma unroll
            for (int j4 = 0; j4 < 10; ++j4) {
                float4 v = ((const float4*)src)[j4];
                wr2[r * 20 + 2 * j4 + 0] = (v2f){v.x, v.y};
                wr2[r * 20 + 2 * j4 + 1] = (v2f){v.z, v.w};
            }
        }
    }

    __syncthreads();   // full fence once; in-loop barriers are raw s_barrier

    for (int c = 0; c < NCHUNK; ++c) {
        if (wid == 0) {
            // ================= recurrence wave: steps 2c, 2c+1 (both batches) =========
            const int s0  = 2 * c;
            const int sl0 = s0 % RING, sl1 = (s0 + 1) % RING;
            float rgA0[2], rgA1[2], rgB0[2] = {0.f, 0.f}, rgB1[2] = {0.f, 0.f};
            #pragma unroll
            for (int pb = 0; pb < 2; ++pb) {
                // ring slots for this chunk are final (taps this chunk write slots >= 2c+2)
                rgA0[pb] = ringp[pb][sl0 * RDIM + rowA];
                rgA1[pb] = ringp[pb][sl1 * RDIM + rowA];
                if (sub == 0) {
                    rgB0[pb] = ringp[pb][sl0 * RDIM + rowB];
                    rgB1[pb] = ringp[pb][sl1 * RDIM + rowB];
                }
                // retire the consumed slots for reuse 169 steps later
                ringp[pb][sl0 * RDIM + rowA] = 0.f; ringp[pb][sl1 * RDIM + rowA] = 0.f;
                if (sub == 0) { ringp[pb][sl0 * RDIM + rowB] = 0.f; ringp[pb][sl1 * RDIM + rowB] = 0.f; }
            }
            // prefetch next chunk's x (8B aligned: s0+2 even)
            float xn0[2] = { x0[0], x0[1] }, xn1[2] = { x1[0], x1[1] };
            if (s0 + 2 < SEQ) {
                #pragma unroll
                for (int pb = 0; pb < 2; ++pb) {
                    float2 xn = *(const float2*)(xb[pb] + s0 + 2);
                    xn0[pb] = xn.x; xn1[pb] = xn.y;
                }
            }

            #pragma unroll
            for (int st = 0; st < 2; ++st) {
                const int s = s0 + st;
                #pragma unroll
                for (int pb = 0; pb < 2; ++pb) {
                    const float xs  = st ? x1[pb]   : x0[pb];
                    const float rgA = st ? rgA1[pb] : rgA0[pb];
                    const float rgB = st ? rgB1[pb] : rgB0[pb];
                    // hh2[pb] already holds the broadcast h_{s-1} slice
                    v2f dd2[5];
                    #pragma unroll
                    for (int r = 0; r < 5; ++r) dd2[r] = (v2f){0.f, 0.f};
                    #pragma unroll
                    for (int r = 0; r < 5; ++r)
                        #pragma unroll
                        for (int j2 = 0; j2 < 10; ++j2)
                            dd2[r] = __builtin_elementwise_fma(wr2[r * 10 + j2], hh2[pb][j2], dd2[r]);
                    float dd[5];
                    #pragma unroll
                    for (int r = 0; r < 5; ++r) dd[r] = dd2[r].x + dd2[r].y;
                    // quad all-reduce: every lane gets full dots for its quad's 5 rows
                    #pragma unroll
                    for (int r = 0; r < 5; ++r) {
                        dd[r] = dpp_xor_add<0xB1>(dd[r]);
                        dd[r] = dpp_xor_add<0x4E>(dd[r]);
                    }
                    float dA = (sub == 0) ? dd[0] : (sub == 1) ? dd[1] : (sub == 2) ? dd[2] : dd[3];
                    float zA = dA + rgA + bA + xs * winA;
                    hA[pb] = 0.7f * hA[pb] + 0.3f * fast_tanh(zA);
                    if (sub == 0) {
                        float zB = dd[4] + rgB + bB + xs * winB;
                        hB[pb] = 0.7f * hB[pb] + 0.3f * fast_tanh(zB);
                    }
                    // publish h_s to LDS history (taps read it next chunk)
                    hhp[pb][(s & 3) * RDIM + rowA] = hA[pb];
                    if (sub == 0) hhp[pb][(s & 3) * RDIM + rowB] = hB[pb];
                    // immediately read back the broadcast slice for step s+1
                    // (same-wave DS ordering; only this wave writes hhp)
                    {
                        const float4* hp = (const float4*)(hhp[pb] + (s & 3) * RDIM + 20 * sub);
                        #pragma unroll
                        for (int j4 = 0; j4 < 5; ++j4) {
                            float4 v = hp[j4];
                            hh2[pb][2 * j4 + 0] = (v2f){v.x, v.y};
                            hh2[pb][2 * j4 + 1] = (v2f){v.z, v.w};
                        }
                    }
                    // fire-and-forget output stores (never read; no vmcnt drain)
                    ob[pb][(size_t)s * RDIM + rowA] = hA[pb];
                    if (sub == 0) ob[pb][(size_t)s * RDIM + rowB] = hB[pb];
                }
            }
            x0[0] = xn0[0]; x0[1] = xn0[1];
            x1[0] = xn1[0]; x1[1] = xn1[1];
        } else if (c > 0) {
            // ===== tap waves: steps 2(c-1), 2(c-1)+1 from LDS h_hist (both batches) ====
            const int sp0 = 2 * (c - 1);
            #pragma unroll
            for (int st = 0; st < 2; ++st) {
                const int sp = sp0 + st;
                const int sl = (sp + tap_tau) % RING;
                v2f ha2[2][20];
                // issue both batches' h loads together (latency paid once)
                #pragma unroll
                for (int pb = 0; pb < 2; ++pb) {
                    const float* hp = hhp[pb] + (sp & 3) * RDIM + 40 * half;
                    #pragma unroll
                    for (int j4 = 0; j4 < 10; ++j4) {
                        float4 v = ((const float4*)hp)[j4];
                        ha2[pb][2 * j4 + 0] = (v2f){v.x, v.y};
                        ha2[pb][2 * j4 + 1] = (v2f){v.z, v.w};
                    }
                }
                #pragma unroll
                for (int pb = 0; pb < 2; ++pb) {
                    v2f dA2[4];
                    #pragma unroll
                    for (int r = 0; r < 4; ++r) dA2[r] = (v2f){0.f, 0.f};
                    #pragma unroll
                    for (int r = 0; r < 4; ++r)
                        #pragma unroll
                        for (int j2 = 0; j2 < 20; ++j2)
                            dA2[r] = __builtin_elementwise_fma(wr2[r * 20 + j2], ha2[pb][j2], dA2[r]);
                    float dA[4];
                    #pragma unroll
                    for (int r = 0; r < 4; ++r) dA[r] = dA2[r].x + dA2[r].y;
                    // combine j-halves across the (even,odd) lane pair
                    #pragma unroll
                    for (int r = 0; r < 4; ++r)
                        dA[r] = dpp_xor_add<0xB1>(dA[r]);
                    if (tap_valid && tap_lo) {
                        float4* pA = (float4*)(ringp[pb] + sl * RDIM + 4 * qq);
                        float4 vA = *pA;
                        vA.x += dA[0]; vA.y += dA[1]; vA.z += dA[2]; vA.w += dA[3];
                        *pA = vA;
                    }
                }
            }
        }
        // LDS-only fence + raw barrier: do NOT drain vmcnt (global stores in flight)
        asm volatile("s_waitcnt lgkmcnt(0)" ::: "memory");
        __builtin_amdgcn_s_barrier();
    }
}

extern "C" void kernel_launch(void* const* d_in, const int* in_sizes, int n_in,
                              void* d_out, int out_size, void* d_ws, size_t ws_size,
                              hipStream_t stream) {
    const float* x    = (const float*)d_in[0];   // (64, 8192, 1)
    const float* W_in = (const float*)d_in[1];   // (80, 1)
    const float* W_fb = (const float*)d_in[2];   // (5, 80, 80)
    const float* bias = (const float*)d_in[3];   // (80,)
    float* out        = (float*)d_out;           // (64, 8192, 80)

    reservoir_kernel<<<BATCH / 2, 256, 0, stream>>>(x, W_in, W_fb, bias, out);
}

// Round 8
// 4680.021 us; speedup vs baseline: 1.5044x; 1.5044x over previous
//
#include <hip/hip_runtime.h>

#define BATCH 64
#define SEQ 8192
#define RDIM 80
#define RING 169          // max delay 168 + 1
#define NCHUNK (SEQ / 2)  // 2 steps per chunk, 1 barrier per chunk

typedef float v2f __attribute__((ext_vector_type(2)));

__device__ __forceinline__ float fast_tanh(float z) {
    // tanh(z) = 1 - 2/(exp(2z)+1); exact saturation, abs err ~1e-7
    float e = __expf(2.0f * z);
    return 1.0f - 2.0f / (e + 1.0f);
}

// v + (v from lane ^ pattern) via DPP quad_perm (pure VALU, no LDS/SGPR hazard)
// 0xB1 = quad_perm(1,0,3,2) -> xor 1 ; 0x4E = quad_perm(2,3,0,1) -> xor 2
template <int CTRL>
__device__ __forceinline__ float dpp_xor_add(float v) {
    int o = __builtin_amdgcn_mov_dpp(__float_as_int(v), CTRL, 0xF, 0xF, true);
    return v + __int_as_float(o);
}

// TWO batches per block via TLP (R6 mechanism), but with the FIXED wave->SIMD
// mapping: SIMD = wid&3, so place rec-A at wid0 (SIMD0) and rec-B at wid5
// (SIMD1) -> the two serial recurrence chains NEVER share an issue port.
// (R6 put both recs on SIMD0 -> chains fought for issue -> regression.)
// Each rec SIMD carries one slack-rich tap wave of the OTHER batch; rec waves
// run at s_setprio(1) so the critical chain wins arbitration.
//   wid: 0=recA  1..3=tapA1..3  4=tapB1  5=recB  6=tapB2  7=tapB3
//   SIMD0: recA+tapB1  SIMD1: recB+tapA1  SIMD2: tapA2+tapB2  SIMD3: tapA3+tapB3
__global__ __attribute__((amdgpu_flat_work_group_size(512, 512)))
void reservoir_kernel(const float* __restrict__ x,
                      const float* __restrict__ W_in,
                      const float* __restrict__ W_fb,
                      const float* __restrict__ bias,
                      float* __restrict__ out) {
    // per-batch: ring[slot][i] = accumulated far-tap contributions for step s = slot (mod 169)
    __shared__ __align__(16) float ring[2 * RING * RDIM];    // 108160 B
    // per-batch: h_hist[s&3][i]: h for step s; rec wave writes, taps + rec-broadcast read
    __shared__ __align__(16) float h_hist[2 * 4 * RDIM];     // 2560 B

    const int t    = threadIdx.x;
    const int wid  = t >> 6;
    const int lane = t & 63;

    int bh, role;
    if (wid == 0)      { bh = 0; role = 0; }
    else if (wid == 5) { bh = 1; role = 0; }
    else if (wid <= 3) { bh = 0; role = wid; }                  // 1,2,3 -> tapA 1..3
    else               { bh = 1; role = (wid == 4) ? 1 : wid - 4; } // 4,6,7 -> tapB 1..3

    const int b = blockIdx.x * 2 + bh;

    for (int i = t; i < 2 * RING * RDIM; i += 512) ring[i] = 0.0f;
    for (int i = t; i < 2 * 4 * RDIM; i += 512) h_hist[i] = 0.0f;

    float* ringp = ring + bh * (RING * RDIM);
    float* hhp   = h_hist + bh * (4 * RDIM);

    const float* xb   = x + (size_t)b * SEQ;
    float*       outb = out + (size_t)b * (size_t)SEQ * RDIM;

    v2f wr2[80];   // per-lane weight slice as packed pairs (rec wave uses first 50)

    // ---- rec-wave layout: quad q owns rows 5q..5q+4; lane (q,sub) covers j in [20*sub, 20*sub+20)
    int q = 0, sub = 0, rowA = 0, rowB = 0;
    float hA = 0.f, hB = 0.f, winA = 0.f, winB = 0.f, bA = 0.f, bB = 0.f;
    v2f hh2[10];   // rec: broadcast h_{s-1} slice (packed), carried across steps
    // ---- tap layout (roles 1..3, both steps of the chunk):
    //      unit g = (role-1)*64+lane < 160 ; k=g/40 -> tau{4,24,96,168};
    //      qq=(g%40)/2 -> rows 4qq..4qq+3 ; half=g&1 -> j in [40*half, 40*half+40)
    int tap_tau = 0, qq = 0, half = 0;
    bool tap_valid = false, tap_lo = false;
    float x0 = 0.f, x1 = 0.f;

    if (role == 0) {
        q = lane >> 2; sub = lane & 3;
        rowA = 5 * q + sub;        // owned by this lane
        rowB = 5 * q + 4;          // owned by sub==0 lane
        #pragma unroll
        for (int r = 0; r < 5; ++r) {
            const float* src = W_fb + (size_t)(5 * q + r) * RDIM + 20 * sub;  // W_1 rows
            #pragma unroll
            for (int j4 = 0; j4 < 5; ++j4) {
                float4 v = ((const float4*)src)[j4];
                wr2[r * 10 + 2 * j4 + 0] = (v2f){v.x, v.y};
                wr2[r * 10 + 2 * j4 + 1] = (v2f){v.z, v.w};
            }
        }
        winA = W_in[rowA]; bA = bias[rowA];
        winB = W_in[rowB]; bB = bias[rowB];
        #pragma unroll
        for (int j2 = 0; j2 < 10; ++j2) hh2[j2] = (v2f){0.f, 0.f};   // h_{-1} = 0
        x0 = xb[0]; x1 = xb[1];
    } else {
        int g = (role - 1) * 64 + lane;
        tap_valid = (g < 160);
        int gg = tap_valid ? g : 159;
        int k = gg / 40, rem = gg % 40;
        qq = rem >> 1; half = rem & 1;
        tap_lo = (half == 0);
        const int taus[4] = {4, 24, 96, 168};
        tap_tau = taus[k];
        #pragma unroll
        for (int r = 0; r < 4; ++r) {
            const float* src = W_fb + (size_t)(k + 1) * RDIM * RDIM
                                    + (size_t)(4 * qq + r) * RDIM + 40 * half;
            #pragma unroll
            for (int j4 = 0; j4 < 10; ++j4) {
                float4 v = ((const float4*)src)[j4];
                wr2[r * 20 + 2 * j4 + 0] = (v2f){v.x, v.y};
                wr2[r * 20 + 2 * j4 + 1] = (v2f){v.z, v.w};
            }
        }
    }

    __syncthreads();   // full fence once; in-loop barriers are raw s_barrier

    // critical-chain waves win issue arbitration against their co-resident tap
    if (role == 0) __builtin_amdgcn_s_setprio(1);

    for (int c = 0; c < NCHUNK; ++c) {
        if (role == 0) {
            // ================= recurrence wave: steps 2c, 2c+1 =================
            const int s0  = 2 * c;
            const int sl0 = s0 % RING, sl1 = (s0 + 1) % RING;
            // ring slots for this chunk are final (taps this chunk write slots >= 2c+2)
            float rgA0 = ringp[sl0 * RDIM + rowA];
            float rgA1 = ringp[sl1 * RDIM + rowA];
            float rgB0 = 0.f, rgB1 = 0.f;
            if (sub == 0) { rgB0 = ringp[sl0 * RDIM + rowB]; rgB1 = ringp[sl1 * RDIM + rowB]; }
            // retire the consumed slots for reuse 169 steps later
            ringp[sl0 * RDIM + rowA] = 0.f; ringp[sl1 * RDIM + rowA] = 0.f;
            if (sub == 0) { ringp[sl0 * RDIM + rowB] = 0.f; ringp[sl1 * RDIM + rowB] = 0.f; }
            // prefetch next chunk's x (8B aligned: s0+2 even)
            float xn0 = x0, xn1 = x1;
            if (s0 + 2 < SEQ) { float2 xn = *(const float2*)(xb + s0 + 2); xn0 = xn.x; xn1 = xn.y; }

            #pragma unroll
            for (int st = 0; st < 2; ++st) {
                const int s     = s0 + st;
                const float xs  = st ? x1   : x0;
                const float rgA = st ? rgA1 : rgA0;
                const float rgB = st ? rgB1 : rgB0;
                // hh2 already holds the broadcast h_{s-1} slice (prefetched last step)
                v2f dd2[5];
                #pragma unroll
                for (int r = 0; r < 5; ++r) dd2[r] = (v2f){0.f, 0.f};
                #pragma unroll
                for (int r = 0; r < 5; ++r)
                    #pragma unroll
                    for (int j2 = 0; j2 < 10; ++j2)
                        dd2[r] = __builtin_elementwise_fma(wr2[r * 10 + j2], hh2[j2], dd2[r]);
                float dd[5];
                #pragma unroll
                for (int r = 0; r < 5; ++r) dd[r] = dd2[r].x + dd2[r].y;
                // quad all-reduce: every lane gets full dots for its quad's 5 rows
                #pragma unroll
                for (int r = 0; r < 5; ++r) {
                    dd[r] = dpp_xor_add<0xB1>(dd[r]);
                    dd[r] = dpp_xor_add<0x4E>(dd[r]);
                }
                float dA = (sub == 0) ? dd[0] : (sub == 1) ? dd[1] : (sub == 2) ? dd[2] : dd[3];
                float zA = dA + rgA + bA + xs * winA;
                hA = 0.7f * hA + 0.3f * fast_tanh(zA);
                if (sub == 0) {
                    float zB = dd[4] + rgB + bB + xs * winB;
                    hB = 0.7f * hB + 0.3f * fast_tanh(zB);
                }
                // publish h_s to LDS history (taps read it next chunk)
                hhp[(s & 3) * RDIM + rowA] = hA;
                if (sub == 0) hhp[(s & 3) * RDIM + rowB] = hB;
                // immediately read back the broadcast slice for step s+1
                // (same-wave DS ordering; only this wave writes hhp)
                {
                    const float4* hp = (const float4*)(hhp + (s & 3) * RDIM + 20 * sub);
                    #pragma unroll
                    for (int j4 = 0; j4 < 5; ++j4) {
                        float4 v = hp[j4];
                        hh2[2 * j4 + 0] = (v2f){v.x, v.y};
                        hh2[2 * j4 + 1] = (v2f){v.z, v.w};
                    }
                }
                // fire-and-forget output stores (never read by anyone; no vmcnt drain)
                outb[(size_t)s * RDIM + rowA] = hA;
                if (sub == 0) outb[(size_t)s * RDIM + rowB] = hB;
            }
            x0 = xn0; x1 = xn1;
        } else if (c > 0) {
            // ===== tap waves: consume steps 2(c-1), 2(c-1)+1 from LDS h_hist =====
            const int sp0 = 2 * (c - 1);
            #pragma unroll
            for (int st = 0; st < 2; ++st) {
                const int sp = sp0 + st;
                const float* hp = hhp + (sp & 3) * RDIM + 40 * half;
                v2f ha2[20];
                #pragma unroll
                for (int j4 = 0; j4 < 10; ++j4) {
                    float4 v = ((const float4*)hp)[j4];
                    ha2[2 * j4 + 0] = (v2f){v.x, v.y};
                    ha2[2 * j4 + 1] = (v2f){v.z, v.w};
                }
                v2f dA2[4];
                #pragma unroll
                for (int r = 0; r < 4; ++r) dA2[r] = (v2f){0.f, 0.f};
                #pragma unroll
                for (int r = 0; r < 4; ++r)
                    #pragma unroll
                    for (int j2 = 0; j2 < 20; ++j2)
                        dA2[r] = __builtin_elementwise_fma(wr2[r * 20 + j2], ha2[j2], dA2[r]);
                float dA[4];
                #pragma unroll
                for (int r = 0; r < 4; ++r) dA[r] = dA2[r].x + dA2[r].y;
                // combine j-halves across the (even,odd) lane pair
                #pragma unroll
                for (int r = 0; r < 4; ++r)
                    dA[r] = dpp_xor_add<0xB1>(dA[r]);
                if (tap_valid && tap_lo) {
                    const int sl = (sp + tap_tau) % RING;
                    float4* pA = (float4*)(ringp + sl * RDIM + 4 * qq);
                    float4 vA = *pA;
                    vA.x += dA[0]; vA.y += dA[1]; vA.z += dA[2]; vA.w += dA[3];
                    *pA = vA;
                }
            }
        }
        // LDS-only fence + raw barrier: do NOT drain vmcnt (global stores in flight)
        asm volatile("s_waitcnt lgkmcnt(0)" ::: "memory");
        __builtin_amdgcn_s_barrier();
    }
}

extern "C" void kernel_launch(void* const* d_in, const int* in_sizes, int n_in,
                              void* d_out, int out_size, void* d_ws, size_t ws_size,
                              hipStream_t stream) {
    const float* x    = (const float*)d_in[0];   // (64, 8192, 1)
    const float* W_in = (const float*)d_in[1];   // (80, 1)
    const float* W_fb = (const float*)d_in[2];   // (5, 80, 80)
    const float* bias = (const float*)d_in[3];   // (80,)
    float* out        = (float*)d_out;           // (64, 8192, 80)

    reservoir_kernel<<<BATCH / 2, 512, 0, stream>>>(x, W_in, W_fb, bias, out);
}